// Round 3
// baseline (294.835 us; speedup 1.0000x reference)
//
#include <hip/hip_runtime.h>
#include <hip/hip_bf16.h>

// B=1024, D_IN=64, H=128, D_OUT=16
// inputs:  fp32  x[1024,64] W1[64,128] b1[128] W2[128,16] b2[16]
// outputs: fp32, flat: f[1024*16] | df[1024*64*16] | d2f[1024*64*64*16]
// ws (bf16): U[4096*128] (U[(k*64+i)][h] = W1[i,h]*W1[k,h]) | Gt[1024*16*128] (Gt[b][j][h] = t_bh*W2[h,j])
//
// Math per sample: z = x@W1+b1, a=tanh(z), s=1-a^2, t=-2*a*s
//   f          = a@W2 + b2
//   df[i,j]    = sum_h W1[i,h] s_h W2[h,j]
//   d2f[k,i,j] = sum_h W1[i,h] W1[k,h] t_h W2[h,j]   (symmetric in i,k)
// d2f_b = (W1 (x) W1) [4096x128] @ (t_b*W2) [128x16]  -> bf16 MFMA batched GEMM, fp32 out.

typedef unsigned short u16;
typedef short s8v __attribute__((ext_vector_type(8)));   // 8 bf16 = 4 VGPRs (A/B frag)
typedef float f4v __attribute__((ext_vector_type(4)));

__device__ __forceinline__ u16 f2bf(float f){
  __hip_bfloat16 h = __float2bfloat16(f);   // RNE
  return __builtin_bit_cast(u16, h);
}

// ---------------- K1: per-sample z,a,s,t ; f ; df ; emit Gt and a slice of U ----------------
__global__ __launch_bounds__(128) void k1_fdf(
    const float* __restrict__ x,  const float* __restrict__ W1, const float* __restrict__ b1,
    const float* __restrict__ W2, const float* __restrict__ b2,
    float* __restrict__ f_out, float* __restrict__ df_out,
    u16* __restrict__ U, u16* __restrict__ Gt)
{
  const int b   = blockIdx.x;   // sample
  const int tid = threadIdx.x;  // 0..127

  __shared__ float sx[64];
  __shared__ float s_a[128];
  __shared__ float s_sw2[128 * 16];   // s_h * W2[h][j]

  // U slice: 512 elements [b*512, b*512+512): U[r][h] = W1[r&63][h]*W1[r>>6][h]
  {
    const int base = b * 512;
#pragma unroll
    for (int u = 0; u < 4; ++u){
      int idx = base + u*128 + tid;
      int r = idx >> 7, h = idx & 127;
      float w = W1[(r & 63)*128 + h] * W1[(r >> 6)*128 + h];
      U[idx] = f2bf(w);
    }
  }

  if (tid < 64) sx[tid] = x[b*64 + tid];
  __syncthreads();

  // z_h for h = tid (W1 column read coalesced across threads)
  float z = b1[tid];
#pragma unroll 8
  for (int i = 0; i < 64; ++i) z += sx[i] * W1[i*128 + tid];
  float a = tanhf(z);
  float s = 1.0f - a*a;        // tanh'
  float t = -2.0f * a * s;     // tanh''
  s_a[tid] = a;
#pragma unroll
  for (int j = 0; j < 16; ++j){
    float w2 = W2[tid*16 + j];
    s_sw2[tid*16 + j] = s * w2;
    Gt[(b*16 + j)*128 + tid] = f2bf(t * w2);   // [b][j][h], h contiguous (B-frag order)
  }
  __syncthreads();

  // f[b,j], j = tid (first 16 lanes)
  if (tid < 16){
    float acc = b2[tid];
    for (int h = 0; h < 128; ++h) acc += s_a[h] * W2[h*16 + tid];
    f_out[b*16 + tid] = acc;
  }

  // df[b,i,j] = sum_h W1[i,h] * (s*W2)[h,j] ; thread -> (i = tid>>1, j0 = (tid&1)*8)
  const int i  = tid >> 1;
  const int j0 = (tid & 1) * 8;
  float acc[8] = {0,0,0,0,0,0,0,0};
  for (int h0 = 0; h0 < 128; h0 += 8){
    const float4* wp = (const float4*)&W1[i*128 + h0];
    float4 wa = wp[0], wb = wp[1];
    float wf[8] = {wa.x, wa.y, wa.z, wa.w, wb.x, wb.y, wb.z, wb.w};
#pragma unroll
    for (int hh = 0; hh < 8; ++hh){
      const float4* sp = (const float4*)&s_sw2[(h0 + hh)*16 + j0];
      float4 A = sp[0], Bv = sp[1];
      float w1 = wf[hh];
      acc[0] += w1*A.x;  acc[1] += w1*A.y;  acc[2] += w1*A.z;  acc[3] += w1*A.w;
      acc[4] += w1*Bv.x; acc[5] += w1*Bv.y; acc[6] += w1*Bv.z; acc[7] += w1*Bv.w;
    }
  }
  float4* dp = (float4*)&df_out[b*1024 + i*16 + j0];
  dp[0] = make_float4(acc[0], acc[1], acc[2], acc[3]);
  dp[1] = make_float4(acc[4], acc[5], acc[6], acc[7]);
}

// ---------------- K2: d2f[b] (4096x16) = U (4096x128) @ G_b (128x16), bf16 MFMA, fp32 out ----
// block = 256 thr (4 waves), handles 4 samples x 1024 U-rows. grid = (256 bgroups, 4 row-chunks)
__global__ __launch_bounds__(256) void k2_d2f(
    const u16* __restrict__ U, const u16* __restrict__ Gt, float* __restrict__ d2f)
{
  const int tid  = threadIdx.x;
  const int lane = tid & 63;
  const int wave = tid >> 6;
  const int n = lane & 15;      // MFMA col / A-row position
  const int q = lane >> 4;      // quad (K-block)
  const int b0 = blockIdx.x * 4;
  const int mb = blockIdx.y;

  // B-fragments: all K=128 for 4 samples, held in registers (64 VGPRs)
  s8v bfrag[4][4];
#pragma unroll
  for (int s = 0; s < 4; ++s){
    const u16* gp = Gt + ((b0 + s)*16 + n)*128 + q*8;
#pragma unroll
    for (int ks = 0; ks < 4; ++ks)
      bfrag[s][ks] = *(const s8v*)(gp + ks*32);
  }

  const int R0 = mb*1024 + wave*256;   // 16 m-tiles of 16 rows per wave
#pragma unroll 2
  for (int mt = 0; mt < 16; ++mt){
    const int rowbase = R0 + mt*16;
    const u16* ap = U + (rowbase + n)*128 + q*8;
    s8v afrag[4];
#pragma unroll
    for (int ks = 0; ks < 4; ++ks)
      afrag[ks] = *(const s8v*)(ap + ks*32);

#pragma unroll
    for (int s = 0; s < 4; ++s){
      f4v acc = {0.f, 0.f, 0.f, 0.f};
#pragma unroll
      for (int ks = 0; ks < 4; ++ks)
        acc = __builtin_amdgcn_mfma_f32_16x16x32_bf16(afrag[ks], bfrag[s][ks], acc, 0, 0, 0);
      // C/D layout: col = lane&15, row = q*4 + reg
      float* op = d2f + (size_t)(b0 + s)*65536 + (rowbase + q*4)*16 + n;
#pragma unroll
      for (int reg = 0; reg < 4; ++reg)
        op[reg*16] = acc[reg];
    }
  }
}

extern "C" void kernel_launch(void* const* d_in, const int* in_sizes, int n_in,
                              void* d_out, int out_size, void* d_ws, size_t ws_size,
                              hipStream_t stream)
{
  (void)in_sizes; (void)n_in; (void)out_size; (void)ws_size;
  const float* x  = (const float*)d_in[0];
  const float* W1 = (const float*)d_in[1];
  const float* b1 = (const float*)d_in[2];
  const float* W2 = (const float*)d_in[3];
  const float* b2 = (const float*)d_in[4];

  float* out     = (float*)d_out;
  float* f_out   = out;                    // 16384
  float* df_out  = out + 16384;            // 1048576
  float* d2f_out = out + 1064960;          // 67108864

  u16* U  = (u16*)d_ws;                    // 524288 bf16 = 1 MB
  u16* Gt = U + 524288;                    // 2097152 bf16 = 4 MB

  k1_fdf<<<1024, 128, 0, stream>>>(x, W1, b1, W2, b2, f_out, df_out, U, Gt);
  k2_d2f<<<dim3(256, 4), 256, 0, stream>>>(U, Gt, d2f_out);
}